// Round 5
// baseline (495.671 us; speedup 1.0000x reference)
//
#include <hip/hip_runtime.h>

#define NNODE 100
#define HDIM  128
#define NEDGE 360
#define NT    512

typedef float f32x4 __attribute__((ext_vector_type(4)));
typedef short s16x8 __attribute__((ext_vector_type(8)));

__device__ __forceinline__ float bf2f(short s) {
  union { unsigned int u; float f; } v;
  v.u = ((unsigned int)(unsigned short)s) << 16;
  return v.f;
}
__device__ __forceinline__ short f2bf(float f) {  // RNE
  union { float f; unsigned int u; } v; v.f = f;
  unsigned int u = v.u + 0x7fffu + ((v.u >> 16) & 1u);
  return (short)(u >> 16);
}
// XOR-swizzled LDS index (shorts). Row stride 128 shorts (256B); 16B groups
// permuted by row&15 so stride-256B row accesses spread across all banks.
__device__ __forceinline__ int sidx(int r, int k) {
  return (r << 7) + ((((k >> 3) ^ (r & 15)) << 3) | (k & 7));
}
// fp32 h-buffer index: row stride 128 floats; columns XOR'd by row-bit so the
// quad-pattern scalar stores land 2-way (free) instead of 4-way on banks.
__device__ __forceinline__ int hidx(int r, int c) {
  return (r << 7) + (c ^ ((r & 4) << 2));
}

// ---------------- merged prep: transposes + fold + edge lists, ONE launch ----
// wt slots (16384 shorts): 0=W1, 1=Wc(=W2@Wu1b), 2=Wu1a, 3=Wu2
__global__ __launch_bounds__(NT)
void prep_all(const float* __restrict__ w_msg1, const float* __restrict__ w_msg2,
              const float* __restrict__ w_upd1, const float* __restrict__ w_upd2,
              const float* __restrict__ b_msg2, const int* __restrict__ dst_idx,
              short* __restrict__ wt, float* __restrict__ bv, int* __restrict__ inl) {
  __shared__ int cnt[NNODE];
  const int bid = blockIdx.x, tid = threadIdx.x;
  if (bid < 96) {
    const int idx = bid * NT + tid;          // < 49152
    const int m = idx >> 14, i = idx & 16383;
    const int n = i >> 7, k = i & 127;
    const float* W = (m == 0) ? w_msg1 : (m == 1) ? w_upd1 : w_upd2;
    const int slot = (m == 0) ? 0 : (m == 1) ? 2 : 3;
    wt[slot * 16384 + n * HDIM + k] = f2bf(W[k * HDIM + n]);
    if (bid == 0) {
      if (tid < NNODE) cnt[tid] = 0;
      __syncthreads();
      if (tid < NEDGE) {
        int d = dst_idx[tid];
        int p = atomicAdd(&cnt[d], 1);
        inl[d * 4 + p] = tid;
      }
      __syncthreads();
      if (tid < NNODE)
        for (int p = cnt[tid]; p < 4; ++p) inl[tid * 4 + p] = -1;
    }
  } else {
    const int u = (bid - 96) * NT + tid;     // < 16896
    const int i = u >> 7, j = u & 127;
    if (i < 128) {
      float s = 0.f;
#pragma unroll 4
      for (int k = 0; k < 128; ++k)
        s += w_msg2[i * HDIM + k] * w_upd1[(HDIM + k) * HDIM + j];
      wt[16384 + j * HDIM + i] = f2bf(s);    // B-layout: [n=j][k=i]
    } else if (i == 128) {
      float s = 0.f;
#pragma unroll 4
      for (int k = 0; k < 128; ++k)
        s += b_msg2[k] * w_upd1[(HDIM + k) * HDIM + j];
      bv[j] = s;
    }
  }
}

// ---------------- main fused kernel: 53584 B LDS -> 3 blocks/CU ----
// 8x16 wave decomposition: each wave owns 16 rows x all 128 cols (acc[8]).
// - magg gathered per-thread into registers inside B1 (no bufM, no P2 phase)
// - LayerNorm wave-local via shfl_xor within 16-lane groups (no lnb exchange)
// - biases read from L2-hot global in epilogues; b1 folded into t at P1
__global__ __launch_bounds__(NT, 6)
void mpnn_main(const float* __restrict__ x,
               const int* __restrict__ src_idx,
               const float* __restrict__ edge_dir,
               const float* __restrict__ w_msg1,   // row 128 = edge-feature column
               const float* __restrict__ b_msg1,
               const float* __restrict__ b_upd1,
               const float* __restrict__ b_upd2,
               const float* __restrict__ gamma,
               const float* __restrict__ beta,
               const short* __restrict__ wt,
               const float* __restrict__ bv_g,
               const int* __restrict__ inl_g,
               float* __restrict__ out)
{
  __shared__ __align__(16) char smem[53584];
  short* bufA = (short*)smem;                  // 25600: x bf16 (stage..B1)
  short* bufB = (short*)(smem + 25600);        // 25600: t' (P1..B1), u1 (B1..B2)
  float* hbuf = (float*)smem;                  // 51200 fp32 final, overlays A+B (B2..)
  short* ep   = (short*)(smem + 51200);        // 768: packed src|dir<<7 (..B1)
  int*   inls = (int*)(smem + 51968);          // 1600 (..B1)
  float* edv  = (float*)(smem + 53568);        // 16: dir code -> exact fp32 dir

  const int tid  = threadIdx.x;
  const int lane = tid & 63;
  const int w    = tid >> 6;    // wave 0..7: rows w*16..w*16+15
  const int quad = lane >> 4;
  const int l16  = lane & 15;
  const int b    = blockIdx.x;
  const float* xb = x + (size_t)b * (NNODE * HDIM);

  const int r0 = w * 16 + l16;
  const int m0 = (r0 < NNODE) ? r0 : 0;   // clamp garbage rows (outputs discarded)

  // per-thread B-fragment base: row(col of C) = ct*16 + l16, k = kq*32 + quad*8
  const int woff = l16 * HDIM + quad * 8;

  // ---- staging ----
  for (int G = tid; G < NNODE * 16; G += NT) {
    int r = G >> 4, g = G & 15;
    const float4* p = (const float4*)(xb + r * HDIM + g * 8);
    float4 v0 = p[0], v1 = p[1];
    s16x8 h;
    h[0] = f2bf(v0.x); h[1] = f2bf(v0.y); h[2] = f2bf(v0.z); h[3] = f2bf(v0.w);
    h[4] = f2bf(v1.x); h[5] = f2bf(v1.y); h[6] = f2bf(v1.z); h[7] = f2bf(v1.w);
    *(s16x8*)&bufA[sidx(r, g * 8)] = h;
  }
  if (tid < 384) {
    int s = (tid < NEDGE) ? src_idx[tid] : 0;
    float e = (tid < NEDGE) ? edge_dir[tid] : 0.f;
    int d = (int)(e * 3.0f + 0.5f);            // dir code 0..3
    ep[tid] = (short)(s | (d << 7));
    if (tid < NEDGE) edv[d] = e;               // benign same-value race
  }
  if (tid < NNODE) ((int4*)inls)[tid] = ((const int4*)inl_g)[tid];
  __syncthreads();

  // ---- P1: t' = x @ W1 + b1 -> bufB (b1 folded here, exits LDS tables) ----
  {
    f32x4 acc[8] = {};
    const short* wb = wt + woff;
#pragma unroll
    for (int kq = 0; kq < 4; ++kq) {
      const int ko = kq * 32 + quad * 8;
      s16x8 a = *(const s16x8*)&bufA[sidx(m0, ko)];
#pragma unroll
      for (int ct = 0; ct < 8; ++ct) {
        s16x8 bw = *(const s16x8*)&wb[ct * 16 * HDIM + kq * 32];
        acc[ct] = __builtin_amdgcn_mfma_f32_16x16x32_bf16(a, bw, acc[ct], 0, 0, 0);
      }
    }
#pragma unroll
    for (int i = 0; i < 4; ++i) {
      const int row = w * 16 + quad * 4 + i;
      if (row < NNODE) {
#pragma unroll
        for (int ct = 0; ct < 8; ++ct) {
          const int col = ct * 16 + l16;
          bufB[sidx(row, col)] = f2bf(acc[ct][i] + b_msg1[col]);
        }
      }
    }
  }
  __syncthreads();

  // ---- B1: u1 = relu(magg @ Wc + x @ Wu1a + bu1 + cnt*bv) -> bufB (over t') ----
  // magg fragment for THIS thread's row gathered in registers per kq: no bufM.
  {
    f32x4 acc[8] = {};
    const short* wbC = wt + 16384 + woff;       // Wc
    const short* wbU = wt + 2 * 16384 + woff;   // Wu1a
    const int4 il = ((const int4*)inls)[m0];
#pragma unroll
    for (int kq = 0; kq < 4; ++kq) {
      const int ko = kq * 32 + quad * 8;
      s16x8 a = *(const s16x8*)&bufA[sidx(m0, ko)];   // x-half A-frag (issue early)
      const float4 wl0 = *(const float4*)&w_msg1[HDIM * HDIM + ko];
      const float4 wl1 = *(const float4*)&w_msg1[HDIM * HDIM + ko + 4];
      float s[8] = {0, 0, 0, 0, 0, 0, 0, 0};
      const int es[4] = {il.x, il.y, il.z, il.w};
#pragma unroll
      for (int j = 0; j < 4; ++j) {
        if (es[j] >= 0) {
          const int pk = ep[es[j]];
          const float ed = edv[pk >> 7];
          s16x8 t8 = *(const s16x8*)&bufB[sidx(pk & 127, ko)];
          float u;
          u = bf2f(t8[0]) + ed * wl0.x; s[0] += u > 0.f ? u : 0.f;
          u = bf2f(t8[1]) + ed * wl0.y; s[1] += u > 0.f ? u : 0.f;
          u = bf2f(t8[2]) + ed * wl0.z; s[2] += u > 0.f ? u : 0.f;
          u = bf2f(t8[3]) + ed * wl0.w; s[3] += u > 0.f ? u : 0.f;
          u = bf2f(t8[4]) + ed * wl1.x; s[4] += u > 0.f ? u : 0.f;
          u = bf2f(t8[5]) + ed * wl1.y; s[5] += u > 0.f ? u : 0.f;
          u = bf2f(t8[6]) + ed * wl1.z; s[6] += u > 0.f ? u : 0.f;
          u = bf2f(t8[7]) + ed * wl1.w; s[7] += u > 0.f ? u : 0.f;
        }
      }
      s16x8 mf;
#pragma unroll
      for (int t = 0; t < 8; ++t) mf[t] = f2bf(s[t]);
#pragma unroll
      for (int ct = 0; ct < 8; ++ct) {
        s16x8 bwC = *(const s16x8*)&wbC[ct * 16 * HDIM + kq * 32];
        acc[ct] = __builtin_amdgcn_mfma_f32_16x16x32_bf16(mf, bwC, acc[ct], 0, 0, 0);
        s16x8 bwU = *(const s16x8*)&wbU[ct * 16 * HDIM + kq * 32];
        acc[ct] = __builtin_amdgcn_mfma_f32_16x16x32_bf16(a, bwU, acc[ct], 0, 0, 0);
      }
    }
    __syncthreads();   // all t' gather-reads done before u1 overwrites bufB
#pragma unroll
    for (int i = 0; i < 4; ++i) {
      const int row = w * 16 + quad * 4 + i;
      if (row < NNODE) {
        const int4 il2 = ((const int4*)inls)[row];
        const float cn = (float)((il2.x >= 0) + (il2.y >= 0) + (il2.z >= 0) + (il2.w >= 0));
#pragma unroll
        for (int ct = 0; ct < 8; ++ct) {
          const int col = ct * 16 + l16;
          float v = acc[ct][i] + b_upd1[col] + cn * bv_g[col];
          bufB[sidx(row, col)] = f2bf(v > 0.f ? v : 0.f);
        }
      }
    }
  }
  __syncthreads();

  // ---- B2: h = u1 @ Wu2 + bu2 + x; wave-local LN; hbuf; coalesced store ----
  {
    f32x4 acc[8] = {};
    const short* wb2 = wt + 3 * 16384 + woff;
#pragma unroll
    for (int kq = 0; kq < 4; ++kq) {
      const int ko = kq * 32 + quad * 8;
      s16x8 a = *(const s16x8*)&bufB[sidx(m0, ko)];
#pragma unroll
      for (int ct = 0; ct < 8; ++ct) {
        s16x8 bw = *(const s16x8*)&wb2[ct * 16 * HDIM + kq * 32];
        acc[ct] = __builtin_amdgcn_mfma_f32_16x16x32_bf16(a, bw, acc[ct], 0, 0, 0);
      }
    }
    __syncthreads();   // all u1 reads done; bufA+bufB become hbuf
#pragma unroll
    for (int i = 0; i < 4; ++i) {
      const int row = w * 16 + quad * 4 + i;
      if (row < NNODE) {
        float h[8];
        float s1 = 0.f, s2 = 0.f;
#pragma unroll
        for (int ct = 0; ct < 8; ++ct) {
          const int col = ct * 16 + l16;
          h[ct] = acc[ct][i] + b_upd2[col] + xb[row * HDIM + col];
          s1 += h[ct]; s2 += h[ct] * h[ct];
        }
        // full row lives in this wave's 16-lane group: reduce across l16 only
#pragma unroll
        for (int off = 8; off > 0; off >>= 1) {
          s1 += __shfl_xor(s1, off, 64);
          s2 += __shfl_xor(s2, off, 64);
        }
        const float mu  = s1 * (1.0f / HDIM);
        const float var = s2 * (1.0f / HDIM) - mu * mu;
        const float rs  = rsqrtf(var + 1e-5f);
#pragma unroll
        for (int ct = 0; ct < 8; ++ct) {
          const int col = ct * 16 + l16;
          hbuf[hidx(row, col)] = (h[ct] - mu) * rs * gamma[col] + beta[col];
        }
      }
    }
    __syncthreads();
    // final: pure copy, fully coalesced float4 stores (512B contiguous per row)
    for (int G = tid; G < NNODE * 32; G += NT) {
      const int row = G >> 5;
      const int c = (G & 31) * 4;
      const float4 v = *(const float4*)&hbuf[hidx(row, c)];
      *(float4*)&out[((size_t)b * NNODE + row) * HDIM + c] = v;
    }
  }
}

extern "C" void kernel_launch(void* const* d_in, const int* in_sizes, int n_in,
                              void* d_out, int out_size, void* d_ws, size_t ws_size,
                              hipStream_t stream) {
  const float* x      = (const float*)d_in[0];
  const int*   src    = (const int*)  d_in[1];
  const int*   dst    = (const int*)  d_in[2];
  const float* ed     = (const float*)d_in[3];
  const float* w_msg1 = (const float*)d_in[4];
  const float* b_msg1 = (const float*)d_in[5];
  const float* w_msg2 = (const float*)d_in[6];
  const float* b_msg2 = (const float*)d_in[7];
  const float* w_upd1 = (const float*)d_in[8];
  const float* b_upd1 = (const float*)d_in[9];
  const float* w_upd2 = (const float*)d_in[10];
  const float* b_upd2 = (const float*)d_in[11];
  const float* gamma  = (const float*)d_in[12];
  const float* beta   = (const float*)d_in[13];
  float* out = (float*)d_out;

  short* wt  = (short*)d_ws;                      // 4 * 32768 B (W1, Wc, Wu1a, Wu2)
  float* bv  = (float*)((char*)d_ws + 131072);    // 512 B
  int*   inl = (int*)((char*)d_ws + 131584);      // 100 * int4

  prep_all<<<129, NT, 0, stream>>>(w_msg1, w_msg2, w_upd1, w_upd2, b_msg2,
                                   dst, wt, bv, inl);

  const int Bsz = in_sizes[0] / (NNODE * HDIM);   // 2048
  mpnn_main<<<Bsz, NT, 0, stream>>>(x, src, ed, w_msg1, b_msg1,
                                    b_upd1, b_upd2, gamma, beta, wt, bv, inl, out);
}

// Round 6
// 478.732 us; speedup vs baseline: 1.0354x; 1.0354x over previous
//
#include <hip/hip_runtime.h>

#define NNODE 100
#define HDIM  128
#define NEDGE 360
#define NT    512

typedef float f32x4 __attribute__((ext_vector_type(4)));
typedef short s16x8 __attribute__((ext_vector_type(8)));

__device__ __forceinline__ float bf2f(short s) {
  union { unsigned int u; float f; } v;
  v.u = ((unsigned int)(unsigned short)s) << 16;
  return v.f;
}
__device__ __forceinline__ short f2bf(float f) {  // RNE
  union { float f; unsigned int u; } v; v.f = f;
  unsigned int u = v.u + 0x7fffu + ((v.u >> 16) & 1u);
  return (short)(u >> 16);
}
// XOR-swizzled LDS index (shorts). Row stride 128 shorts (256B); 16B groups
// permuted by row&15 so stride-256B row accesses spread across all banks.
__device__ __forceinline__ int sidx(int r, int k) {
  return (r << 7) + ((((k >> 3) ^ (r & 15)) << 3) | (k & 7));
}

// ---------------- merged prep: transposes + fold + edge lists, ONE launch ----
// wt slots (16384 shorts): 0=W1, 1=Wc(=W2@Wu1b), 2=Wu1a, 3=Wu2
__global__ __launch_bounds__(NT)
void prep_all(const float* __restrict__ w_msg1, const float* __restrict__ w_msg2,
              const float* __restrict__ w_upd1, const float* __restrict__ w_upd2,
              const float* __restrict__ b_msg2, const int* __restrict__ dst_idx,
              short* __restrict__ wt, float* __restrict__ bv, int* __restrict__ inl) {
  __shared__ int cnt[NNODE];
  const int bid = blockIdx.x, tid = threadIdx.x;
  if (bid < 96) {
    const int idx = bid * NT + tid;          // < 49152
    const int m = idx >> 14, i = idx & 16383;
    const int n = i >> 7, k = i & 127;
    const float* W = (m == 0) ? w_msg1 : (m == 1) ? w_upd1 : w_upd2;
    const int slot = (m == 0) ? 0 : (m == 1) ? 2 : 3;
    wt[slot * 16384 + n * HDIM + k] = f2bf(W[k * HDIM + n]);
    if (bid == 0) {
      if (tid < NNODE) cnt[tid] = 0;
      __syncthreads();
      if (tid < NEDGE) {
        int d = dst_idx[tid];
        int p = atomicAdd(&cnt[d], 1);
        inl[d * 4 + p] = tid;
      }
      __syncthreads();
      if (tid < NNODE)
        for (int p = cnt[tid]; p < 4; ++p) inl[tid * 4 + p] = -1;
    }
  } else {
    const int u = (bid - 96) * NT + tid;     // < 16896
    const int i = u >> 7, j = u & 127;
    if (i < 128) {
      float s = 0.f;
#pragma unroll 4
      for (int k = 0; k < 128; ++k)
        s += w_msg2[i * HDIM + k] * w_upd1[(HDIM + k) * HDIM + j];
      wt[16384 + j * HDIM + i] = f2bf(s);    // B-layout: [n=j][k=i]
    } else if (i == 128) {
      float s = 0.f;
#pragma unroll 4
      for (int k = 0; k < 128; ++k)
        s += b_msg2[k] * w_upd1[(HDIM + k) * HDIM + j];
      bv[j] = s;
    }
  }
}

// ---------------- main fused kernel: 44880 B LDS, TWO barriers ----
// 8x16 wave decomposition. x lives only in registers (xa[4], reused P1+B1).
// bufT holds t' then (in-place, after barrier B) u1. All writes/reads except the
// B1 gather are wave-local rows -> only 2 __syncthreads in the whole kernel.
// LN staged per-wave in hsl slices for coalesced float4 stores.
__global__ __launch_bounds__(NT, 5)
void mpnn_main(const float* __restrict__ x,
               const int* __restrict__ src_idx,
               const float* __restrict__ edge_dir,
               const float* __restrict__ w_msg1,   // row 128 = edge-feature column
               const float* __restrict__ b_msg1,
               const float* __restrict__ b_upd1,
               const float* __restrict__ b_upd2,
               const float* __restrict__ gamma,
               const float* __restrict__ beta,
               const short* __restrict__ wt,
               const float* __restrict__ bv_g,
               const int* __restrict__ inl_g,
               float* __restrict__ out)
{
  __shared__ __align__(16) char smem[44880];
  short* bufT = (short*)smem;                 // 25600: t' (P1..B1), u1 (B1..B2) in-place
  float* hsl  = (float*)(smem + 25600);       // 16896: 8 waves x 4x132 fp32 LN slices
  short* ep   = (short*)(smem + 42496);       // 768: packed src|dir<<7
  int*   inls = (int*)(smem + 43264);         // 1600
  float* edv  = (float*)(smem + 44864);       // 16: dir code -> exact fp32 dir

  const int tid  = threadIdx.x;
  const int lane = tid & 63;
  const int w    = tid >> 6;    // wave 0..7: rows w*16..w*16+15
  const int quad = lane >> 4;
  const int l16  = lane & 15;
  const int b    = blockIdx.x;
  const float* xb = x + (size_t)b * (NNODE * HDIM);

  const int r0 = w * 16 + l16;
  const int m0 = (r0 < NNODE) ? r0 : 0;   // clamp garbage rows (outputs discarded)
  const int woff = l16 * HDIM + quad * 8;

  // ---- tables (first read is after barrier A) ----
  if (tid < 384) {
    int s = (tid < NEDGE) ? src_idx[tid] : 0;
    float e = (tid < NEDGE) ? edge_dir[tid] : 0.f;
    int d = (int)(e * 3.0f + 0.5f);            // dir code 0..3
    ep[tid] = (short)(s | (d << 7));
    if (tid < NEDGE) edv[d] = e;               // benign same-value race
  }
  if (tid < NNODE) ((int4*)inls)[tid] = ((const int4*)inl_g)[tid];

  // ---- x A-fragments global->regs: read ONCE, used in P1 and B1 ----
  s16x8 xa[4];
#pragma unroll
  for (int kq = 0; kq < 4; ++kq) {
    const float4* p = (const float4*)(xb + m0 * HDIM + kq * 32 + quad * 8);
    float4 v0 = p[0], v1 = p[1];
    s16x8 a;
    a[0] = f2bf(v0.x); a[1] = f2bf(v0.y); a[2] = f2bf(v0.z); a[3] = f2bf(v0.w);
    a[4] = f2bf(v1.x); a[5] = f2bf(v1.y); a[6] = f2bf(v1.z); a[7] = f2bf(v1.w);
    xa[kq] = a;
  }

  // ---- P1: t' = x @ W1 + b1 -> bufT (wave-local rows) ----
  {
    f32x4 acc[8] = {};
    const short* wb = wt + woff;
#pragma unroll
    for (int kq = 0; kq < 4; ++kq)
#pragma unroll
      for (int ct = 0; ct < 8; ++ct) {
        s16x8 bw = *(const s16x8*)&wb[ct * 16 * HDIM + kq * 32];
        acc[ct] = __builtin_amdgcn_mfma_f32_16x16x32_bf16(xa[kq], bw, acc[ct], 0, 0, 0);
      }
    float bm1c[8];
#pragma unroll
    for (int ct = 0; ct < 8; ++ct) bm1c[ct] = b_msg1[ct * 16 + l16];
#pragma unroll
    for (int i = 0; i < 4; ++i) {
      const int row = w * 16 + quad * 4 + i;
      if (row < NNODE) {
#pragma unroll
        for (int ct = 0; ct < 8; ++ct)
          bufT[sidx(row, ct * 16 + l16)] = f2bf(acc[ct][i] + bm1c[ct]);
      }
    }
  }
  __syncthreads();   // barrier A: t' complete (gather reads cross-wave rows)

  // ---- B1: u1 = relu(magg @ Wc + x @ Wu1a + bu1 + cnt*bv) -> bufT in-place ----
  {
    // gather magg A-fragment for row m0 into mf[4] (register-only, no bufM)
    s16x8 mf[4];
    const int4 il = ((const int4*)inls)[m0];
    const int es[4] = {il.x, il.y, il.z, il.w};
#pragma unroll
    for (int kq = 0; kq < 4; ++kq) {
      const int ko = kq * 32 + quad * 8;
      const float4 wl0 = *(const float4*)&w_msg1[HDIM * HDIM + ko];
      const float4 wl1 = *(const float4*)&w_msg1[HDIM * HDIM + ko + 4];
      float s[8] = {0, 0, 0, 0, 0, 0, 0, 0};
#pragma unroll
      for (int j = 0; j < 4; ++j) {
        if (es[j] >= 0) {
          const int pk = ep[es[j]];
          const float ed = edv[pk >> 7];
          s16x8 t8 = *(const s16x8*)&bufT[sidx(pk & 127, ko)];
          float u;
          u = bf2f(t8[0]) + ed * wl0.x; s[0] += u > 0.f ? u : 0.f;
          u = bf2f(t8[1]) + ed * wl0.y; s[1] += u > 0.f ? u : 0.f;
          u = bf2f(t8[2]) + ed * wl0.z; s[2] += u > 0.f ? u : 0.f;
          u = bf2f(t8[3]) + ed * wl0.w; s[3] += u > 0.f ? u : 0.f;
          u = bf2f(t8[4]) + ed * wl1.x; s[4] += u > 0.f ? u : 0.f;
          u = bf2f(t8[5]) + ed * wl1.y; s[5] += u > 0.f ? u : 0.f;
          u = bf2f(t8[6]) + ed * wl1.z; s[6] += u > 0.f ? u : 0.f;
          u = bf2f(t8[7]) + ed * wl1.w; s[7] += u > 0.f ? u : 0.f;
        }
      }
      s16x8 m8;
#pragma unroll
      for (int t = 0; t < 8; ++t) m8[t] = f2bf(s[t]);
      mf[kq] = m8;
    }
    f32x4 acc[8] = {};
    const short* wbC = wt + 16384 + woff;       // Wc
    const short* wbU = wt + 2 * 16384 + woff;   // Wu1a
#pragma unroll
    for (int kq = 0; kq < 4; ++kq)
#pragma unroll
      for (int ct = 0; ct < 8; ++ct) {
        s16x8 bwC = *(const s16x8*)&wbC[ct * 16 * HDIM + kq * 32];
        acc[ct] = __builtin_amdgcn_mfma_f32_16x16x32_bf16(mf[kq], bwC, acc[ct], 0, 0, 0);
        s16x8 bwU = *(const s16x8*)&wbU[ct * 16 * HDIM + kq * 32];
        acc[ct] = __builtin_amdgcn_mfma_f32_16x16x32_bf16(xa[kq], bwU, acc[ct], 0, 0, 0);
      }
    __syncthreads();   // barrier B: every wave's gather reads done; t' may die
    float bu1c[8], bvc[8];
#pragma unroll
    for (int ct = 0; ct < 8; ++ct) {
      bu1c[ct] = b_upd1[ct * 16 + l16];
      bvc[ct]  = bv_g[ct * 16 + l16];
    }
#pragma unroll
    for (int i = 0; i < 4; ++i) {
      const int row = w * 16 + quad * 4 + i;
      if (row < NNODE) {
        const int4 il2 = ((const int4*)inls)[row];
        const float cn = (float)((il2.x >= 0) + (il2.y >= 0) + (il2.z >= 0) + (il2.w >= 0));
#pragma unroll
        for (int ct = 0; ct < 8; ++ct) {
          float v = acc[ct][i] + bu1c[ct] + cn * bvc[ct];
          bufT[sidx(row, ct * 16 + l16)] = f2bf(v > 0.f ? v : 0.f);
        }
      }
    }
  }
  // NO barrier: B2 reads only this wave's own u1 rows (lgkmcnt ordering suffices;
  // clamped rows >=100 may read stale data that only feeds discarded outputs)

  // ---- B2: h = u1 @ Wu2 + bu2 + x; wave-local LN; per-wave LDS slice; store ----
  {
    f32x4 acc[8] = {};
    const short* wb2 = wt + 3 * 16384 + woff;
#pragma unroll
    for (int kq = 0; kq < 4; ++kq) {
      const int ko = kq * 32 + quad * 8;
      s16x8 a = *(const s16x8*)&bufT[sidx(m0, ko)];
#pragma unroll
      for (int ct = 0; ct < 8; ++ct) {
        s16x8 bw = *(const s16x8*)&wb2[ct * 16 * HDIM + kq * 32];
        acc[ct] = __builtin_amdgcn_mfma_f32_16x16x32_bf16(a, bw, acc[ct], 0, 0, 0);
      }
    }
    float bu2c[8], gmc[8], btc[8];
#pragma unroll
    for (int ct = 0; ct < 8; ++ct) {
      const int col = ct * 16 + l16;
      bu2c[ct] = b_upd2[col];
      gmc[ct]  = gamma[col];
      btc[ct]  = beta[col];
    }
    float* hs = hsl + w * 528;   // this wave's slice: 4 rows x 132 fp32
    float* outb = out + (size_t)b * (NNODE * HDIM);
#pragma unroll
    for (int i = 0; i < 4; ++i) {
      const int row = w * 16 + quad * 4 + i;
      if (row < NNODE) {
        float h[8];
        float s1 = 0.f, s2 = 0.f;
#pragma unroll
        for (int ct = 0; ct < 8; ++ct) {
          h[ct] = acc[ct][i] + bu2c[ct] + xb[row * HDIM + ct * 16 + l16];
          s1 += h[ct]; s2 += h[ct] * h[ct];
        }
        // row's 128 cols live in this 16-lane group: reduce across l16 only
#pragma unroll
        for (int off = 8; off > 0; off >>= 1) {
          s1 += __shfl_xor(s1, off, 64);
          s2 += __shfl_xor(s2, off, 64);
        }
        const float mu  = s1 * (1.0f / HDIM);
        const float var = s2 * (1.0f / HDIM) - mu * mu;
        const float rs  = rsqrtf(var + 1e-5f);
#pragma unroll
        for (int ct = 0; ct < 8; ++ct)
          hs[quad * 132 + ct * 16 + l16] = (h[ct] - mu) * rs * gmc[ct] + btc[ct];
      }
      // wave-local transpose read + fully coalesced float4 stores (512B per row)
      const int rowg = w * 16 + quad * 4 + i;   // lane>>4 == quad
      if (rowg < NNODE) {
        const int c0 = l16 * 8;
        float4 v0 = *(const float4*)&hs[quad * 132 + c0];
        float4 v1 = *(const float4*)&hs[quad * 132 + c0 + 4];
        *(float4*)&outb[rowg * HDIM + c0]     = v0;
        *(float4*)&outb[rowg * HDIM + c0 + 4] = v1;
      }
    }
  }
}

extern "C" void kernel_launch(void* const* d_in, const int* in_sizes, int n_in,
                              void* d_out, int out_size, void* d_ws, size_t ws_size,
                              hipStream_t stream) {
  const float* x      = (const float*)d_in[0];
  const int*   src    = (const int*)  d_in[1];
  const int*   dst    = (const int*)  d_in[2];
  const float* ed     = (const float*)d_in[3];
  const float* w_msg1 = (const float*)d_in[4];
  const float* b_msg1 = (const float*)d_in[5];
  const float* w_msg2 = (const float*)d_in[6];
  const float* b_msg2 = (const float*)d_in[7];
  const float* w_upd1 = (const float*)d_in[8];
  const float* b_upd1 = (const float*)d_in[9];
  const float* w_upd2 = (const float*)d_in[10];
  const float* b_upd2 = (const float*)d_in[11];
  const float* gamma  = (const float*)d_in[12];
  const float* beta   = (const float*)d_in[13];
  float* out = (float*)d_out;

  short* wt  = (short*)d_ws;                      // 4 * 32768 B (W1, Wc, Wu1a, Wu2)
  float* bv  = (float*)((char*)d_ws + 131072);    // 512 B
  int*   inl = (int*)((char*)d_ws + 131584);      // 100 * int4

  prep_all<<<129, NT, 0, stream>>>(w_msg1, w_msg2, w_upd1, w_upd2, b_msg2,
                                   dst, wt, bv, inl);

  const int Bsz = in_sizes[0] / (NNODE * HDIM);   // 2048
  mpnn_main<<<Bsz, NT, 0, stream>>>(x, src, ed, w_msg1, b_msg1,
                                    b_upd1, b_upd2, gamma, beta, wt, bv, inl, out);
}